// Round 19
// baseline (164.561 us; speedup 1.0000x reference)
//
#include <hip/hip_runtime.h>

// N=4, C=32(n_feats), H=W=300, P=5 fixed by setup_inputs.
#define HW        90000
#define OUT_HALF  11520000
#define CPLANE    11520000ull            // shorts per conv plane
#define WPACK_OFF  46080000ull
#define ZOFF       46227456              // 64B zero block
#define JB_OFF     46227520
#define WS_NEED    (46227520ull + 230400ull)

typedef short short4v __attribute__((ext_vector_type(4)));
typedef short short8 __attribute__((ext_vector_type(8)));
typedef int   int4v  __attribute__((ext_vector_type(4)));
typedef float f32x4  __attribute__((ext_vector_type(4)));
typedef unsigned int u32;

__device__ inline short f2bf(float f) {
    unsigned u = __builtin_bit_cast(unsigned, f);
    u += 0x7fff + ((u >> 16) & 1);            // RNE
    return (short)(u >> 16);
}
__device__ inline float bf2f(short s) {
    unsigned u = ((unsigned)(unsigned short)s) << 16;
    return __builtin_bit_cast(float, u);
}
__device__ inline void gload16(char* ldst, const char* gsrc) {
    __builtin_amdgcn_global_load_lds(
        (const __attribute__((address_space(1))) u32*)gsrc,
        (__attribute__((address_space(3))) u32*)ldst, 16, 0, 0);
}

// ---- weight pack for mfma_f32_16x16x32_bf16 A-operand, gamma folded in ----
__global__ __launch_bounds__(256)
void pack_weights(const float* __restrict__ wR, const float* __restrict__ wH,
                  const float* __restrict__ rg, const float* __restrict__ hg,
                  short* __restrict__ wpack) {
    int id = blockIdx.x * 256 + threadIdx.x;   // 73728
    if (id >= 73728) return;
    int e    = id & 7;
    int lane = (id >> 3) & 63;
    int h    = (id >> 9) & 1;
    int t    = (id >> 10) % 9;
    int kb   = ((id >> 10) / 9) & 3;
    int conv = id / 36864;
    int co   = h * 16 + (lane & 15);
    int cin  = kb * 32 + (lane >> 4) * 8 + e;
    const float* w = conv ? wH : wR;
    const float* g = conv ? hg : rg;
    wpack[id] = f2bf(w[(co * 128 + cin) * 9 + t] * g[cin >> 5]);
}

// ---- patch-base table: jb[n][j][k] = plane-relative byte offset of patch jp ----
__global__ __launch_bounds__(256)
void pack_jb(const int* __restrict__ corr, int* __restrict__ jb) {
    int id = blockIdx.x * 256 + threadIdx.x;   // 57600
    if (id >= 57600) return;
    int k = id & 3, j = (id >> 2) % 3600, n = id / 14400;
    int jp = (k == 0) ? j : corr[(n * 3600 + j) * 4 + k];
    jb[id] = ((jp / 60) * 1500 + (jp % 60) * 5) * 64;
}

// ---- NCHW f32 -> per-conv NHWC bf16 planes ----
__global__ __launch_bounds__(256)
void nchw2nhwc(const float* __restrict__ xrgb, const float* __restrict__ yhsi,
               short* __restrict__ cmb) {
    int wave = threadIdx.x >> 6, lane = threadIdx.x & 63;
    if (lane >= 60) return;
    int y = blockIdx.y * 4 + wave;
    int x = blockIdx.x * 60 + lane;
    int n = blockIdx.z;
    const float* xb = xrgb + n * 32 * HW + y * 300 + x;
    const float* yb = yhsi + n * 32 * HW + y * 300 + x;
    size_t pxo = ((size_t)n * HW + y * 300 + x) * 32;
    short* d0 = cmb + pxo;
    short* d1 = cmb + CPLANE + pxo;
    #pragma unroll
    for (int q = 0; q < 4; ++q) {
        short8 v0, v1;
        #pragma unroll
        for (int e = 0; e < 8; ++e) {
            int c = q * 8 + e;
            v0[e] = f2bf((c < 16) ? xb[(16 + c) * HW] : yb[c * HW]);
            v1[e] = f2bf((c < 16) ? xb[c * HW] : yb[(c - 16) * HW]);
        }
        *(short8*)(d0 + q * 8) = v0;
        *(short8*)(d1 + q * 8) = v1;
    }
}

// ---- conv: 12x16 tile, halo 14x18=252px, ALL 4 k-slots staged once (63KB LDS),
// ---- ONE barrier, then straight-line 432-MFMA compute with zero syncs ----
__global__ __launch_bounds__(256, 2)
void conv_mfma(const char* __restrict__ wsbase, const short* __restrict__ wpack,
               const float* __restrict__ bR, const float* __restrict__ bH,
               float* __restrict__ out) {
    __shared__ alignas(16) char lds[64512];      // 252 px x 256B (4 k-slots)
    int tile = blockIdx.x;
    int n = blockIdx.y;
    int conv = blockIdx.z;
    int ty = tile / 19, tx = tile - ty * 19;
    int y0 = ty * 12, x0 = tx * 16;
    int tid = threadIdx.x;
    int wave = tid >> 6, lane = tid & 63;

    const short* cmb = (const short*)wsbase + conv * CPLANE + (size_t)n * HW * 32;
    const short* wp  = wpack + conv * 36864;
    int cmb_byte = (int)(conv * (CPLANE * 2)) + n * (HW * 64);
    const int* jbtab = (const int*)(wsbase + JB_OFF);

    // ---- staging precompute: 63 instrs, instr j4 covers px 4*j4..4*j4+3 (256B each).
    // lane's physical slot: off = j4*1024 + lane*16 -> px = off>>8,
    // low8 = (lane&15)<<4, unswz = low8 ^ ((px&7)<<4), k = unswz>>6, chunk = unswz&48.
    int soff[16];
    #pragma unroll
    for (int ji = 0; ji < 16; ++ji) {
        int j4 = wave + ji * 4;
        int px = j4 * 4 + (lane >> 4);           // 0..251 (valid when j4<63)
        int un = ((lane & 15) << 4) ^ ((px & 7) << 4);
        int k  = (un >> 6) & 3;
        int chunk = un & 48;
        soff[ji] = ZOFF + chunk;
        if (j4 < 63) {
            int hr = px / 18, hc = px - hr * 18;
            int gy = y0 + hr - 1, gx = x0 + hc - 1;
            if (gy >= 0 && gy < 300 && gx >= 0 && gx < 300) {
                int pr = gy / 5, pc = gx / 5;
                int j  = pr * 60 + pc;
                int intra = (gy - pr * 5) * 300 + (gx - pc * 5);
                soff[ji] = cmb_byte + jbtab[(n * 3600 + j) * 4 + k] + intra * 64 + chunk;
            }
        }
    }

    // issue all 63 gathers (16 per wave), then the single barrier
    #pragma unroll
    for (int ji = 0; ji < 16; ++ji) {
        int j4 = wave + ji * 4;
        if (j4 < 63)
            gload16(&lds[j4 * 1024], wsbase + soff[ji]);
    }

    int l15 = lane & 15, lh = lane >> 4;
    int wr = wave * 3;                       // wave's first output row (0..9)

    // B-offsets for kb=0; kb folds in as ^(kb<<6) (pb bits 6-7 are zero)
    int boff0[3][5];
    #pragma unroll
    for (int dxi = 0; dxi < 3; ++dxi)
        #pragma unroll
        for (int rr = 0; rr < 5; ++rr) {
            int hp = (wr + rr) * 18 + (l15 + dxi);
            boff0[dxi][rr] = (hp * 256 + lh * 16) ^ ((hp & 7) << 4);
        }

    __syncthreads();

    f32x4 acc[3][2];
    #pragma unroll
    for (int g = 0; g < 3; ++g)
        #pragma unroll
        for (int h = 0; h < 2; ++h)
            acc[g][h] = (f32x4){0.f, 0.f, 0.f, 0.f};

    __builtin_amdgcn_s_setprio(1);
    #pragma unroll
    for (int kb = 0; kb < 4; ++kb) {
        #pragma unroll
        for (int dxi = 0; dxi < 3; ++dxi) {
            short8 a[3][2];
            #pragma unroll
            for (int dyi = 0; dyi < 3; ++dyi) {
                int t = dyi * 3 + dxi;
                a[dyi][0] = *(const short8*)(wp + (((kb * 9 + t) * 2 + 0) * 64 + lane) * 8);
                a[dyi][1] = *(const short8*)(wp + (((kb * 9 + t) * 2 + 1) * 64 + lane) * 8);
            }
            short8 b[5];
            #pragma unroll
            for (int rr = 0; rr < 5; ++rr)
                b[rr] = *(const short8*)(lds + (boff0[dxi][rr] ^ (kb << 6)));
            #pragma unroll
            for (int g = 0; g < 3; ++g) {
                #pragma unroll
                for (int dyi = 0; dyi < 3; ++dyi) {
                    acc[g][0] = __builtin_amdgcn_mfma_f32_16x16x32_bf16(a[dyi][0], b[g + dyi], acc[g][0], 0, 0, 0);
                    acc[g][1] = __builtin_amdgcn_mfma_f32_16x16x32_bf16(a[dyi][1], b[g + dyi], acc[g][1], 0, 0, 0);
                }
            }
        }
    }
    __builtin_amdgcn_s_setprio(0);

    // epilogue: residual via two short4 loads (gy always < 300: 25*12=300)
    const float* bias = conv ? bH : bR;
    float bia[2][4];
    #pragma unroll
    for (int h = 0; h < 2; ++h)
        #pragma unroll
        for (int reg = 0; reg < 4; ++reg)
            bia[h][reg] = bias[h * 16 + lh * 4 + reg];
    #pragma unroll
    for (int g = 0; g < 3; ++g) {
        int gy = y0 + wr + g;
        int gx = x0 + l15;
        if (gx < 300) {
            int pixo = gy * 300 + gx;
            const short* resp = cmb + (size_t)pixo * 32 + lh * 4;
            #pragma unroll
            for (int h = 0; h < 2; ++h) {
                short4v r = *(const short4v*)(resp + h * 16);
                #pragma unroll
                for (int reg = 0; reg < 4; ++reg) {
                    int co = h * 16 + lh * 4 + reg;
                    out[conv * OUT_HALF + (n * 32 + co) * HW + pixo]
                        = acc[g][h][reg] + bia[h][reg] + bf2f(r[reg]);
                }
            }
        }
    }
}

// ---- fallback (round-1 kernel) if ws too small ----
__global__ __launch_bounds__(256)
void fused_gather_conv(const float* __restrict__ xrgb, const float* __restrict__ yhsi,
                       const int* __restrict__ corr, const float* __restrict__ rgb_gamma,
                       const float* __restrict__ hsi_gamma, const float* __restrict__ wR,
                       const float* __restrict__ bR, const float* __restrict__ wH,
                       const float* __restrict__ bH, float* __restrict__ out) {
    int tid = blockIdx.x * blockDim.x + threadIdx.x;
    if (tid >= 4 * HW) return;
    int n = tid / HW, pix = tid - n * HW;
    int y = pix / 300, x = pix - y * 300;
    const int* idx = corr + n * (3600 * 4);
    const float* xb = xrgb + n * (32 * HW);
    const float* yb = yhsi + n * (32 * HW);
    float accR[32], accH[32];
    #pragma unroll
    for (int i = 0; i < 32; ++i) { accR[i] = 0.f; accH[i] = 0.f; }
    for (int k = 0; k < 4; ++k) {
        float gr = rgb_gamma[k], gh = hsi_gamma[k];
        int off[9];
        #pragma unroll
        for (int t = 0; t < 9; ++t) {
            int dy = t / 3 - 1, dx = t % 3 - 1;
            int yy = y + dy, xx = x + dx;
            int o = -1;
            if (yy >= 0 && yy < 300 && xx >= 0 && xx < 300) {
                int pr = yy / 5, pc = xx / 5;
                int j = pr * 60 + pc;
                int jp = (k == 0) ? j : idx[j * 4 + k];
                o = ((jp / 60) * 5 + (yy - pr * 5)) * 300 + (jp % 60) * 5 + (xx - pc * 5);
            }
            off[t] = o;
        }
        for (int c = 0; c < 32; ++c) {
            const float* srcR = (c < 16) ? (xb + (16 + c) * HW) : (yb + c * HW);
            const float* srcH = (c < 16) ? (xb + c * HW) : (yb + (c - 16) * HW);
            float vr[9], vh[9];
            #pragma unroll
            for (int t = 0; t < 9; ++t) {
                bool vld = off[t] >= 0;
                vr[t] = vld ? gr * srcR[off[t]] : 0.f;
                vh[t] = vld ? gh * srcH[off[t]] : 0.f;
            }
            const float* wRp = wR + (k * 32 + c) * 9;
            const float* wHp = wH + (k * 32 + c) * 9;
            #pragma unroll
            for (int t = 0; t < 9; ++t)
                #pragma unroll
                for (int co = 0; co < 32; ++co) {
                    accR[co] = fmaf(vr[t], wRp[co * 1152 + t], accR[co]);
                    accH[co] = fmaf(vh[t], wHp[co * 1152 + t], accH[co]);
                }
        }
    }
    #pragma unroll
    for (int co = 0; co < 32; ++co) {
        float resR = (co < 16) ? xb[(16 + co) * HW + pix] : yb[co * HW + pix];
        float resH = (co < 16) ? xb[co * HW + pix] : yb[(co - 16) * HW + pix];
        out[(n * 32 + co) * HW + pix]            = accR[co] + bR[co] + resR;
        out[OUT_HALF + (n * 32 + co) * HW + pix] = accH[co] + bH[co] + resH;
    }
}

extern "C" void kernel_launch(void* const* d_in, const int* in_sizes, int n_in,
                              void* d_out, int out_size, void* d_ws, size_t ws_size,
                              hipStream_t stream) {
    const float* xrgb = (const float*)d_in[0];
    const float* yhsi = (const float*)d_in[1];
    const int*   corr = (const int*)d_in[2];
    const float* rg   = (const float*)d_in[3];
    const float* hg   = (const float*)d_in[4];
    const float* wR   = (const float*)d_in[5];
    const float* bR   = (const float*)d_in[6];
    const float* wH   = (const float*)d_in[7];
    const float* bH   = (const float*)d_in[8];
    float* out = (float*)d_out;

    if (ws_size >= WS_NEED) {
        char* ws = (char*)d_ws;
        hipMemsetAsync(ws + ZOFF, 0, 64, stream);
        hipLaunchKernelGGL(pack_weights, dim3(288), dim3(256), 0, stream,
                           wR, wH, rg, hg, (short*)(ws + WPACK_OFF));
        hipLaunchKernelGGL(pack_jb, dim3(225), dim3(256), 0, stream,
                           corr, (int*)(ws + JB_OFF));
        hipLaunchKernelGGL(nchw2nhwc, dim3(5, 75, 4), dim3(256), 0, stream,
                           xrgb, yhsi, (short*)ws);
        hipLaunchKernelGGL(conv_mfma, dim3(475, 4, 2), dim3(256), 0, stream,
                           (const char*)ws, (const short*)(ws + WPACK_OFF), bR, bH, out);
    } else {
        int total = 4 * HW;
        hipLaunchKernelGGL(fused_gather_conv, dim3((total + 255) / 256), dim3(256), 0, stream,
                           xrgb, yhsi, corr, rg, hg, wR, bR, wH, bH, out);
    }
}

// Round 20
// 133.848 us; speedup vs baseline: 1.2295x; 1.2295x over previous
//
#include <hip/hip_runtime.h>

// N=4, C=32(n_feats), H=W=300, P=5 fixed by setup_inputs.
#define HW        90000
#define OUT_HALF  11520000
#define CPLANE    11520000ull            // shorts per conv plane
#define WPACK_OFF  46080000ull
#define ZOFF       46227456              // 64B zero block
#define JB_OFF     46227520
#define WS_NEED    (46227520ull + 230400ull)

typedef short short4v __attribute__((ext_vector_type(4)));
typedef short short8 __attribute__((ext_vector_type(8)));
typedef int   int4v  __attribute__((ext_vector_type(4)));
typedef float f32x4  __attribute__((ext_vector_type(4)));
typedef unsigned int u32;

__device__ inline short f2bf(float f) {
    unsigned u = __builtin_bit_cast(unsigned, f);
    u += 0x7fff + ((u >> 16) & 1);            // RNE
    return (short)(u >> 16);
}
__device__ inline float bf2f(short s) {
    unsigned u = ((unsigned)(unsigned short)s) << 16;
    return __builtin_bit_cast(float, u);
}
__device__ inline void gload16(char* ldst, const char* gsrc) {
    __builtin_amdgcn_global_load_lds(
        (const __attribute__((address_space(1))) u32*)gsrc,
        (__attribute__((address_space(3))) u32*)ldst, 16, 0, 0);
}

// ---- weight pack for mfma_f32_16x16x32_bf16 A-operand, gamma folded in ----
__global__ __launch_bounds__(256)
void pack_weights(const float* __restrict__ wR, const float* __restrict__ wH,
                  const float* __restrict__ rg, const float* __restrict__ hg,
                  short* __restrict__ wpack) {
    int id = blockIdx.x * 256 + threadIdx.x;   // 73728
    if (id >= 73728) return;
    int e    = id & 7;
    int lane = (id >> 3) & 63;
    int h    = (id >> 9) & 1;
    int t    = (id >> 10) % 9;
    int kb   = ((id >> 10) / 9) & 3;
    int conv = id / 36864;
    int co   = h * 16 + (lane & 15);
    int cin  = kb * 32 + (lane >> 4) * 8 + e;
    const float* w = conv ? wH : wR;
    const float* g = conv ? hg : rg;
    wpack[id] = f2bf(w[(co * 128 + cin) * 9 + t] * g[cin >> 5]);
}

// ---- patch-base table: jb[n][j][k] = plane-relative byte offset of patch jp ----
__global__ __launch_bounds__(256)
void pack_jb(const int* __restrict__ corr, int* __restrict__ jb) {
    int id = blockIdx.x * 256 + threadIdx.x;   // 57600
    if (id >= 57600) return;
    int k = id & 3, j = (id >> 2) % 3600, n = id / 14400;
    int jp = (k == 0) ? j : corr[(n * 3600 + j) * 4 + k];
    jb[id] = ((jp / 60) * 1500 + (jp % 60) * 5) * 64;
}

// ---- NCHW f32 -> per-conv NHWC bf16 planes ----
__global__ __launch_bounds__(256)
void nchw2nhwc(const float* __restrict__ xrgb, const float* __restrict__ yhsi,
               short* __restrict__ cmb) {
    int wave = threadIdx.x >> 6, lane = threadIdx.x & 63;
    if (lane >= 60) return;
    int y = blockIdx.y * 4 + wave;
    int x = blockIdx.x * 60 + lane;
    int n = blockIdx.z;
    const float* xb = xrgb + n * 32 * HW + y * 300 + x;
    const float* yb = yhsi + n * 32 * HW + y * 300 + x;
    size_t pxo = ((size_t)n * HW + y * 300 + x) * 32;
    short* d0 = cmb + pxo;
    short* d1 = cmb + CPLANE + pxo;
    #pragma unroll
    for (int q = 0; q < 4; ++q) {
        short8 v0, v1;
        #pragma unroll
        for (int e = 0; e < 8; ++e) {
            int c = q * 8 + e;
            v0[e] = f2bf((c < 16) ? xb[(16 + c) * HW] : yb[c * HW]);
            v1[e] = f2bf((c < 16) ? xb[c * HW] : yb[(c - 16) * HW]);
        }
        *(short8*)(d0 + q * 8) = v0;
        *(short8*)(d1 + q * 8) = v1;
    }
}

// ---- conv: 16x16 tile, slots 1-3 LDS-staged (dbuf 43KB), kb0 B direct from
// ---- global (identity gather = per-lane contiguous). 3 barriers total. ----
__global__ __launch_bounds__(256, 3)
void conv_mfma(const char* __restrict__ wsbase, const short* __restrict__ wpack,
               const float* __restrict__ bR, const float* __restrict__ bH,
               float* __restrict__ out) {
    __shared__ alignas(16) char lds[2][21504];
    int tile = blockIdx.x;
    int n = blockIdx.y;
    int conv = blockIdx.z;
    int ty = tile / 19, tx = tile - ty * 19;
    int y0 = ty * 16, x0 = tx * 16;
    int tid = threadIdx.x;
    int wave = tid >> 6, lane = tid & 63;

    const short* cmb = (const short*)wsbase + conv * CPLANE + (size_t)n * HW * 32;
    const short* wp  = wpack + conv * 36864;
    int cmb_byte = (int)(conv * (CPLANE * 2)) + n * (HW * 64);
    const int* jbtab = (const int*)(wsbase + JB_OFF);

    int l15 = lane & 15, lh = lane >> 4;
    int wr = wave * 4;

    // staging precompute for slots 1..3 (jb table)
    int soffB[6][3];
    #pragma unroll
    for (int ji = 0; ji < 6; ++ji) {
        int j4 = wave + ji * 4;
        #pragma unroll
        for (int k = 0; k < 3; ++k) soffB[ji][k] = ZOFF;
        if (j4 < 21) {
            int off = j4 * 1024 + lane * 16;
            int pxp = off >> 6;
            int pxl = pxp ^ ((pxp >> 2) & 1);              // inverse of write swizzle
            int cl  = ((off >> 4) & 3) ^ (pxl & 3);
            int cb  = cl * 16;
            #pragma unroll
            for (int k = 0; k < 3; ++k) soffB[ji][k] = ZOFF + cb;
            if (pxl < 324) {
                int hr = pxl / 18, hc = pxl - hr * 18;
                int gy = y0 + hr - 1, gx = x0 + hc - 1;
                if (gy >= 0 && gy < 300 && gx >= 0 && gx < 300) {
                    int pr = gy / 5, pc = gx / 5;
                    int j  = pr * 60 + pc;
                    int intra = (gy - pr * 5) * 300 + (gx - pc * 5);
                    int4v jbv = *(const int4v*)(jbtab + (n * 3600 + j) * 4);
                    int base = cmb_byte + intra * 64 + cb;
                    soffB[ji][0] = base + jbv[1];
                    soffB[ji][1] = base + jbv[2];
                    soffB[ji][2] = base + jbv[3];
                }
            }
        }
    }

    // kb0 global B byte-offsets: goff[dxi][rr], identity patch (per-lane address)
    int goff[3][6];
    #pragma unroll
    for (int dxi = 0; dxi < 3; ++dxi)
        #pragma unroll
        for (int rr = 0; rr < 6; ++rr) {
            int gy = y0 + wr + rr - 1;
            int gx = x0 + l15 + dxi - 1;
            bool v = (gy >= 0 && gy < 300 && gx >= 0 && gx < 300);
            goff[dxi][rr] = v ? (cmb_byte + (gy * 300 + gx) * 64 + lh * 16)
                              : (ZOFF + lh * 16);
        }

    #define STAGE(buf, k)                                                        \
        do {                                                                     \
            _Pragma("unroll")                                                    \
            for (int ji = 0; ji < 6; ++ji) {                                     \
                int j4 = wave + ji * 4;                                          \
                if (j4 < 21)                                                     \
                    gload16(&lds[buf][j4 * 1024], wsbase + soffB[ji][(k)]);      \
            }                                                                    \
        } while (0)

    int boff[3][6];
    #pragma unroll
    for (int dxi = 0; dxi < 3; ++dxi)
        #pragma unroll
        for (int rr = 0; rr < 6; ++rr) {
            int hp = (wr + rr) * 18 + (l15 + dxi);
            boff[dxi][rr] = (hp * 64 + lh * 16) ^ ((hp & 7) << 4);
        }

    STAGE(0, 0);            // slot 1 -> buf0
    __syncthreads();

    f32x4 acc[4][2];
    #pragma unroll
    for (int g = 0; g < 4; ++g)
        #pragma unroll
        for (int h = 0; h < 2; ++h)
            acc[g][h] = (f32x4){0.f, 0.f, 0.f, 0.f};

    // phases kb = 1,2,3 from LDS (stage next slot during compute)
    #pragma unroll
    for (int ph = 0; ph < 3; ++ph) {
        const int kb = ph + 1;
        // (1) A-frags — oldest vmem
        short8 a[3][3][2];
        #pragma unroll
        for (int dxi = 0; dxi < 3; ++dxi)
            #pragma unroll
            for (int dyi = 0; dyi < 3; ++dyi) {
                int t = dyi * 3 + dxi;
                a[dxi][dyi][0] = *(const short8*)(wp + (((kb * 9 + t) * 2 + 0) * 64 + lane) * 8);
                a[dxi][dyi][1] = *(const short8*)(wp + (((kb * 9 + t) * 2 + 1) * 64 + lane) * 8);
            }
        __builtin_amdgcn_sched_barrier(0);
        // (2) stage next slot — youngest vmem
        if (ph == 0) STAGE(1, 1);
        if (ph == 1) STAGE(0, 2);
        __builtin_amdgcn_sched_barrier(0);
        // (3) compute from buf[ph&1]
        const char* base = lds[ph & 1];
        __builtin_amdgcn_s_setprio(1);
        #pragma unroll
        for (int dxi = 0; dxi < 3; ++dxi) {
            short8 b[6];
            #pragma unroll
            for (int rr = 0; rr < 6; ++rr)
                b[rr] = *(const short8*)(base + boff[dxi][rr]);
            #pragma unroll
            for (int g = 0; g < 4; ++g) {
                #pragma unroll
                for (int dyi = 0; dyi < 3; ++dyi) {
                    acc[g][0] = __builtin_amdgcn_mfma_f32_16x16x32_bf16(a[dxi][dyi][0], b[g + dyi], acc[g][0], 0, 0, 0);
                    acc[g][1] = __builtin_amdgcn_mfma_f32_16x16x32_bf16(a[dxi][dyi][1], b[g + dyi], acc[g][1], 0, 0, 0);
                }
            }
        }
        __builtin_amdgcn_s_setprio(0);
        if (ph < 2) __syncthreads();
    }

    // phase kb = 0: B direct from global (identity patch), no barrier needed
    {
        const int kb = 0;
        __builtin_amdgcn_s_setprio(1);
        #pragma unroll
        for (int dxi = 0; dxi < 3; ++dxi) {
            short8 b[6];
            #pragma unroll
            for (int rr = 0; rr < 6; ++rr)
                b[rr] = *(const short8*)(wsbase + goff[dxi][rr]);
            short8 a[3][2];
            #pragma unroll
            for (int dyi = 0; dyi < 3; ++dyi) {
                int t = dyi * 3 + dxi;
                a[dyi][0] = *(const short8*)(wp + (((kb * 9 + t) * 2 + 0) * 64 + lane) * 8);
                a[dyi][1] = *(const short8*)(wp + (((kb * 9 + t) * 2 + 1) * 64 + lane) * 8);
            }
            #pragma unroll
            for (int g = 0; g < 4; ++g) {
                #pragma unroll
                for (int dyi = 0; dyi < 3; ++dyi) {
                    acc[g][0] = __builtin_amdgcn_mfma_f32_16x16x32_bf16(a[dyi][0], b[g + dyi], acc[g][0], 0, 0, 0);
                    acc[g][1] = __builtin_amdgcn_mfma_f32_16x16x32_bf16(a[dyi][1], b[g + dyi], acc[g][1], 0, 0, 0);
                }
            }
        }
        __builtin_amdgcn_s_setprio(0);
    }

    // epilogue: residual via two short4 loads
    const float* bias = conv ? bH : bR;
    float bia[2][4];
    #pragma unroll
    for (int h = 0; h < 2; ++h)
        #pragma unroll
        for (int reg = 0; reg < 4; ++reg)
            bia[h][reg] = bias[h * 16 + lh * 4 + reg];
    #pragma unroll
    for (int g = 0; g < 4; ++g) {
        int gy = y0 + wr + g;
        int gx = x0 + l15;
        if (gy < 300 && gx < 300) {
            int pixo = gy * 300 + gx;
            const short* resp = cmb + (size_t)pixo * 32 + lh * 4;
            #pragma unroll
            for (int h = 0; h < 2; ++h) {
                short4v r = *(const short4v*)(resp + h * 16);
                #pragma unroll
                for (int reg = 0; reg < 4; ++reg) {
                    int co = h * 16 + lh * 4 + reg;
                    out[conv * OUT_HALF + (n * 32 + co) * HW + pixo]
                        = acc[g][h][reg] + bia[h][reg] + bf2f(r[reg]);
                }
            }
        }
    }
    #undef STAGE
}

// ---- fallback (round-1 kernel) if ws too small ----
__global__ __launch_bounds__(256)
void fused_gather_conv(const float* __restrict__ xrgb, const float* __restrict__ yhsi,
                       const int* __restrict__ corr, const float* __restrict__ rgb_gamma,
                       const float* __restrict__ hsi_gamma, const float* __restrict__ wR,
                       const float* __restrict__ bR, const float* __restrict__ wH,
                       const float* __restrict__ bH, float* __restrict__ out) {
    int tid = blockIdx.x * blockDim.x + threadIdx.x;
    if (tid >= 4 * HW) return;
    int n = tid / HW, pix = tid - n * HW;
    int y = pix / 300, x = pix - y * 300;
    const int* idx = corr + n * (3600 * 4);
    const float* xb = xrgb + n * (32 * HW);
    const float* yb = yhsi + n * (32 * HW);
    float accR[32], accH[32];
    #pragma unroll
    for (int i = 0; i < 32; ++i) { accR[i] = 0.f; accH[i] = 0.f; }
    for (int k = 0; k < 4; ++k) {
        float gr = rgb_gamma[k], gh = hsi_gamma[k];
        int off[9];
        #pragma unroll
        for (int t = 0; t < 9; ++t) {
            int dy = t / 3 - 1, dx = t % 3 - 1;
            int yy = y + dy, xx = x + dx;
            int o = -1;
            if (yy >= 0 && yy < 300 && xx >= 0 && xx < 300) {
                int pr = yy / 5, pc = xx / 5;
                int j = pr * 60 + pc;
                int jp = (k == 0) ? j : idx[j * 4 + k];
                o = ((jp / 60) * 5 + (yy - pr * 5)) * 300 + (jp % 60) * 5 + (xx - pc * 5);
            }
            off[t] = o;
        }
        for (int c = 0; c < 32; ++c) {
            const float* srcR = (c < 16) ? (xb + (16 + c) * HW) : (yb + c * HW);
            const float* srcH = (c < 16) ? (xb + c * HW) : (yb + (c - 16) * HW);
            float vr[9], vh[9];
            #pragma unroll
            for (int t = 0; t < 9; ++t) {
                bool vld = off[t] >= 0;
                vr[t] = vld ? gr * srcR[off[t]] : 0.f;
                vh[t] = vld ? gh * srcH[off[t]] : 0.f;
            }
            const float* wRp = wR + (k * 32 + c) * 9;
            const float* wHp = wH + (k * 32 + c) * 9;
            #pragma unroll
            for (int t = 0; t < 9; ++t)
                #pragma unroll
                for (int co = 0; co < 32; ++co) {
                    accR[co] = fmaf(vr[t], wRp[co * 1152 + t], accR[co]);
                    accH[co] = fmaf(vh[t], wHp[co * 1152 + t], accH[co]);
                }
        }
    }
    #pragma unroll
    for (int co = 0; co < 32; ++co) {
        float resR = (co < 16) ? xb[(16 + co) * HW + pix] : yb[co * HW + pix];
        float resH = (co < 16) ? xb[co * HW + pix] : yb[(co - 16) * HW + pix];
        out[(n * 32 + co) * HW + pix]            = accR[co] + bR[co] + resR;
        out[OUT_HALF + (n * 32 + co) * HW + pix] = accH[co] + bH[co] + resH;
    }
}

extern "C" void kernel_launch(void* const* d_in, const int* in_sizes, int n_in,
                              void* d_out, int out_size, void* d_ws, size_t ws_size,
                              hipStream_t stream) {
    const float* xrgb = (const float*)d_in[0];
    const float* yhsi = (const float*)d_in[1];
    const int*   corr = (const int*)d_in[2];
    const float* rg   = (const float*)d_in[3];
    const float* hg   = (const float*)d_in[4];
    const float* wR   = (const float*)d_in[5];
    const float* bR   = (const float*)d_in[6];
    const float* wH   = (const float*)d_in[7];
    const float* bH   = (const float*)d_in[8];
    float* out = (float*)d_out;

    if (ws_size >= WS_NEED) {
        char* ws = (char*)d_ws;
        hipMemsetAsync(ws + ZOFF, 0, 64, stream);
        hipLaunchKernelGGL(pack_weights, dim3(288), dim3(256), 0, stream,
                           wR, wH, rg, hg, (short*)(ws + WPACK_OFF));
        hipLaunchKernelGGL(pack_jb, dim3(225), dim3(256), 0, stream,
                           corr, (int*)(ws + JB_OFF));
        hipLaunchKernelGGL(nchw2nhwc, dim3(5, 75, 4), dim3(256), 0, stream,
                           xrgb, yhsi, (short*)ws);
        hipLaunchKernelGGL(conv_mfma, dim3(361, 4, 2), dim3(256), 0, stream,
                           (const char*)ws, (const short*)(ws + WPACK_OFF), bR, bH, out);
    } else {
        int total = 4 * HW;
        hipLaunchKernelGGL(fused_gather_conv, dim3((total + 255) / 256), dim3(256), 0, stream,
                           xrgb, yhsi, corr, rg, hg, wR, bR, wH, bH, out);
    }
}

// Round 21
// 125.662 us; speedup vs baseline: 1.3095x; 1.0651x over previous
//
#include <hip/hip_runtime.h>

// N=4, C=32(n_feats), H=W=300, P=5 fixed by setup_inputs.
#define HW        90000
#define OUT_HALF  11520000
#define CPLANE    11520000ull            // shorts per conv plane
#define WPACK_OFF  46080000ull
#define ZOFF       46227456              // 64B zero block
#define JB_OFF     46227520
#define WS_NEED    (46227520ull + 230400ull)

typedef short short4v __attribute__((ext_vector_type(4)));
typedef short short8 __attribute__((ext_vector_type(8)));
typedef int   int4v  __attribute__((ext_vector_type(4)));
typedef float f32x4  __attribute__((ext_vector_type(4)));
typedef unsigned int u32;

__device__ inline short f2bf(float f) {
    unsigned u = __builtin_bit_cast(unsigned, f);
    u += 0x7fff + ((u >> 16) & 1);            // RNE
    return (short)(u >> 16);
}
__device__ inline float bf2f(short s) {
    unsigned u = ((unsigned)(unsigned short)s) << 16;
    return __builtin_bit_cast(float, u);
}
__device__ inline void gload16(char* ldst, const char* gsrc) {
    __builtin_amdgcn_global_load_lds(
        (const __attribute__((address_space(1))) u32*)gsrc,
        (__attribute__((address_space(3))) u32*)ldst, 16, 0, 0);
}

// ---- weight pack for mfma_f32_16x16x32_bf16 A-operand, gamma folded in ----
__global__ __launch_bounds__(256)
void pack_weights(const float* __restrict__ wR, const float* __restrict__ wH,
                  const float* __restrict__ rg, const float* __restrict__ hg,
                  short* __restrict__ wpack) {
    int id = blockIdx.x * 256 + threadIdx.x;   // 73728
    if (id >= 73728) return;
    int e    = id & 7;
    int lane = (id >> 3) & 63;
    int h    = (id >> 9) & 1;
    int t    = (id >> 10) % 9;
    int kb   = ((id >> 10) / 9) & 3;
    int conv = id / 36864;
    int co   = h * 16 + (lane & 15);
    int cin  = kb * 32 + (lane >> 4) * 8 + e;
    const float* w = conv ? wH : wR;
    const float* g = conv ? hg : rg;
    wpack[id] = f2bf(w[(co * 128 + cin) * 9 + t] * g[cin >> 5]);
}

// ---- patch-base table: jb[n][j][k] = plane-relative byte offset of patch jp ----
__global__ __launch_bounds__(256)
void pack_jb(const int* __restrict__ corr, int* __restrict__ jb) {
    int id = blockIdx.x * 256 + threadIdx.x;   // 57600
    if (id >= 57600) return;
    int k = id & 3, j = (id >> 2) % 3600, n = id / 14400;
    int jp = (k == 0) ? j : corr[(n * 3600 + j) * 4 + k];
    jb[id] = ((jp / 60) * 1500 + (jp % 60) * 5) * 64;
}

// ---- NCHW f32 -> per-conv NHWC bf16 planes ----
__global__ __launch_bounds__(256)
void nchw2nhwc(const float* __restrict__ xrgb, const float* __restrict__ yhsi,
               short* __restrict__ cmb) {
    int wave = threadIdx.x >> 6, lane = threadIdx.x & 63;
    if (lane >= 60) return;
    int y = blockIdx.y * 4 + wave;
    int x = blockIdx.x * 60 + lane;
    int n = blockIdx.z;
    const float* xb = xrgb + n * 32 * HW + y * 300 + x;
    const float* yb = yhsi + n * 32 * HW + y * 300 + x;
    size_t pxo = ((size_t)n * HW + y * 300 + x) * 32;
    short* d0 = cmb + pxo;
    short* d1 = cmb + CPLANE + pxo;
    #pragma unroll
    for (int q = 0; q < 4; ++q) {
        short8 v0, v1;
        #pragma unroll
        for (int e = 0; e < 8; ++e) {
            int c = q * 8 + e;
            v0[e] = f2bf((c < 16) ? xb[(16 + c) * HW] : yb[c * HW]);
            v1[e] = f2bf((c < 16) ? xb[c * HW] : yb[(c - 16) * HW]);
        }
        *(short8*)(d0 + q * 8) = v0;
        *(short8*)(d1 + q * 8) = v1;
    }
}

// ---- conv: 20x16 tile (300=15x20 exact), 5 rows/wave, halo 22x18=396px
// ---- (pad 400), dbuf 51.2KB -> 3 blocks/CU; r16 phase structure ----
__global__ __launch_bounds__(256, 3)
void conv_mfma(const char* __restrict__ wsbase, const short* __restrict__ wpack,
               const float* __restrict__ bR, const float* __restrict__ bH,
               float* __restrict__ out) {
    __shared__ alignas(16) char lds[2][25600];   // 2 x 400px x 64B
    int tile = blockIdx.x;
    int n = blockIdx.y;
    int conv = blockIdx.z;
    int ty = tile / 19, tx = tile - ty * 19;
    int y0 = ty * 20, x0 = tx * 16;
    int tid = threadIdx.x;
    int wave = tid >> 6, lane = tid & 63;

    const short* cmb = (const short*)wsbase + conv * CPLANE + (size_t)n * HW * 32;
    const short* wp  = wpack + conv * 36864;
    int cmb_byte = (int)(conv * (CPLANE * 2)) + n * (HW * 64);
    const int* jbtab = (const int*)(wsbase + JB_OFF);

    // staging precompute via jb table; instr j4 = wave + ji*4, j4 < 25
    int soffB[7][4];
    #pragma unroll
    for (int ji = 0; ji < 7; ++ji) {
        int j4 = wave + ji * 4;
        #pragma unroll
        for (int k = 0; k < 4; ++k) soffB[ji][k] = ZOFF;
        if (j4 < 25) {
            int off = j4 * 1024 + lane * 16;
            int pxp = off >> 6;
            int pxl = pxp ^ ((pxp >> 2) & 1);              // inverse of write swizzle
            int cl  = ((off >> 4) & 3) ^ (pxl & 3);
            int cb  = cl * 16;
            #pragma unroll
            for (int k = 0; k < 4; ++k) soffB[ji][k] = ZOFF + cb;
            if (pxl < 396) {
                int hr = pxl / 18, hc = pxl - hr * 18;
                int gy = y0 + hr - 1, gx = x0 + hc - 1;
                if (gy >= 0 && gy < 300 && gx >= 0 && gx < 300) {
                    int pr = gy / 5, pc = gx / 5;
                    int j  = pr * 60 + pc;
                    int intra = (gy - pr * 5) * 300 + (gx - pc * 5);
                    int4v jbv = *(const int4v*)(jbtab + (n * 3600 + j) * 4);
                    int base = cmb_byte + intra * 64 + cb;
                    soffB[ji][0] = base + jbv[0];
                    soffB[ji][1] = base + jbv[1];
                    soffB[ji][2] = base + jbv[2];
                    soffB[ji][3] = base + jbv[3];
                }
            }
        }
    }

    #define STAGE(buf, k)                                                        \
        do {                                                                     \
            _Pragma("unroll")                                                    \
            for (int ji = 0; ji < 7; ++ji) {                                     \
                int j4 = wave + ji * 4;                                          \
                if (j4 < 25)                                                     \
                    gload16(&lds[buf][j4 * 1024], wsbase + soffB[ji][(k)]);      \
            }                                                                    \
        } while (0)

    int l15 = lane & 15, lh = lane >> 4;
    int wr = wave * 5;                       // wave's first output row (0..15)

    // B-offsets (kb-invariant): rows wr-1 .. wr+5 (rr = 0..6)
    int boff[3][7];
    #pragma unroll
    for (int dxi = 0; dxi < 3; ++dxi)
        #pragma unroll
        for (int rr = 0; rr < 7; ++rr) {
            int hp = (wr + rr) * 18 + (l15 + dxi);
            boff[dxi][rr] = (hp * 64 + lh * 16) ^ ((hp & 7) << 4);
        }

    STAGE(0, 0);
    __syncthreads();

    f32x4 acc[5][2];
    #pragma unroll
    for (int g = 0; g < 5; ++g)
        #pragma unroll
        for (int h = 0; h < 2; ++h)
            acc[g][h] = (f32x4){0.f, 0.f, 0.f, 0.f};

    #pragma unroll
    for (int kb = 0; kb < 4; ++kb) {
        // (1) A-frags — oldest vmem of the phase
        short8 a[3][3][2];
        #pragma unroll
        for (int dxi = 0; dxi < 3; ++dxi)
            #pragma unroll
            for (int dyi = 0; dyi < 3; ++dyi) {
                int t = dyi * 3 + dxi;
                a[dxi][dyi][0] = *(const short8*)(wp + (((kb * 9 + t) * 2 + 0) * 64 + lane) * 8);
                a[dxi][dyi][1] = *(const short8*)(wp + (((kb * 9 + t) * 2 + 1) * 64 + lane) * 8);
            }
        __builtin_amdgcn_sched_barrier(0);
        // (2) gathers for next buffer — youngest vmem, drain at end-of-phase barrier
        if (kb == 0) STAGE(1, 1);
        if (kb == 1) STAGE(0, 2);
        if (kb == 2) STAGE(1, 3);
        __builtin_amdgcn_sched_barrier(0);
        // (3) compute (T5 priority through the MFMA cluster)
        const char* base = lds[kb & 1];
        __builtin_amdgcn_s_setprio(1);
        #pragma unroll
        for (int dxi = 0; dxi < 3; ++dxi) {
            short8 b[7];
            #pragma unroll
            for (int rr = 0; rr < 7; ++rr)
                b[rr] = *(const short8*)(base + boff[dxi][rr]);
            #pragma unroll
            for (int g = 0; g < 5; ++g) {
                #pragma unroll
                for (int dyi = 0; dyi < 3; ++dyi) {
                    acc[g][0] = __builtin_amdgcn_mfma_f32_16x16x32_bf16(a[dxi][dyi][0], b[g + dyi], acc[g][0], 0, 0, 0);
                    acc[g][1] = __builtin_amdgcn_mfma_f32_16x16x32_bf16(a[dxi][dyi][1], b[g + dyi], acc[g][1], 0, 0, 0);
                }
            }
        }
        __builtin_amdgcn_s_setprio(0);
        if (kb < 3) __syncthreads();
    }

    // epilogue: residual via two short4 loads (gy always < 300: 15*20=300)
    const float* bias = conv ? bH : bR;
    float bia[2][4];
    #pragma unroll
    for (int h = 0; h < 2; ++h)
        #pragma unroll
        for (int reg = 0; reg < 4; ++reg)
            bia[h][reg] = bias[h * 16 + lh * 4 + reg];
    #pragma unroll
    for (int g = 0; g < 5; ++g) {
        int gy = y0 + wr + g;
        int gx = x0 + l15;
        if (gx < 300) {
            int pixo = gy * 300 + gx;
            const short* resp = cmb + (size_t)pixo * 32 + lh * 4;
            #pragma unroll
            for (int h = 0; h < 2; ++h) {
                short4v r = *(const short4v*)(resp + h * 16);
                #pragma unroll
                for (int reg = 0; reg < 4; ++reg) {
                    int co = h * 16 + lh * 4 + reg;
                    out[conv * OUT_HALF + (n * 32 + co) * HW + pixo]
                        = acc[g][h][reg] + bia[h][reg] + bf2f(r[reg]);
                }
            }
        }
    }
    #undef STAGE
}

// ---- fallback (round-1 kernel) if ws too small ----
__global__ __launch_bounds__(256)
void fused_gather_conv(const float* __restrict__ xrgb, const float* __restrict__ yhsi,
                       const int* __restrict__ corr, const float* __restrict__ rgb_gamma,
                       const float* __restrict__ hsi_gamma, const float* __restrict__ wR,
                       const float* __restrict__ bR, const float* __restrict__ wH,
                       const float* __restrict__ bH, float* __restrict__ out) {
    int tid = blockIdx.x * blockDim.x + threadIdx.x;
    if (tid >= 4 * HW) return;
    int n = tid / HW, pix = tid - n * HW;
    int y = pix / 300, x = pix - y * 300;
    const int* idx = corr + n * (3600 * 4);
    const float* xb = xrgb + n * (32 * HW);
    const float* yb = yhsi + n * (32 * HW);
    float accR[32], accH[32];
    #pragma unroll
    for (int i = 0; i < 32; ++i) { accR[i] = 0.f; accH[i] = 0.f; }
    for (int k = 0; k < 4; ++k) {
        float gr = rgb_gamma[k], gh = hsi_gamma[k];
        int off[9];
        #pragma unroll
        for (int t = 0; t < 9; ++t) {
            int dy = t / 3 - 1, dx = t % 3 - 1;
            int yy = y + dy, xx = x + dx;
            int o = -1;
            if (yy >= 0 && yy < 300 && xx >= 0 && xx < 300) {
                int pr = yy / 5, pc = xx / 5;
                int j = pr * 60 + pc;
                int jp = (k == 0) ? j : idx[j * 4 + k];
                o = ((jp / 60) * 5 + (yy - pr * 5)) * 300 + (jp % 60) * 5 + (xx - pc * 5);
            }
            off[t] = o;
        }
        for (int c = 0; c < 32; ++c) {
            const float* srcR = (c < 16) ? (xb + (16 + c) * HW) : (yb + c * HW);
            const float* srcH = (c < 16) ? (xb + c * HW) : (yb + (c - 16) * HW);
            float vr[9], vh[9];
            #pragma unroll
            for (int t = 0; t < 9; ++t) {
                bool vld = off[t] >= 0;
                vr[t] = vld ? gr * srcR[off[t]] : 0.f;
                vh[t] = vld ? gh * srcH[off[t]] : 0.f;
            }
            const float* wRp = wR + (k * 32 + c) * 9;
            const float* wHp = wH + (k * 32 + c) * 9;
            #pragma unroll
            for (int t = 0; t < 9; ++t)
                #pragma unroll
                for (int co = 0; co < 32; ++co) {
                    accR[co] = fmaf(vr[t], wRp[co * 1152 + t], accR[co]);
                    accH[co] = fmaf(vh[t], wHp[co * 1152 + t], accH[co]);
                }
        }
    }
    #pragma unroll
    for (int co = 0; co < 32; ++co) {
        float resR = (co < 16) ? xb[(16 + co) * HW + pix] : yb[co * HW + pix];
        float resH = (co < 16) ? xb[co * HW + pix] : yb[(co - 16) * HW + pix];
        out[(n * 32 + co) * HW + pix]            = accR[co] + bR[co] + resR;
        out[OUT_HALF + (n * 32 + co) * HW + pix] = accH[co] + bH[co] + resH;
    }
}

extern "C" void kernel_launch(void* const* d_in, const int* in_sizes, int n_in,
                              void* d_out, int out_size, void* d_ws, size_t ws_size,
                              hipStream_t stream) {
    const float* xrgb = (const float*)d_in[0];
    const float* yhsi = (const float*)d_in[1];
    const int*   corr = (const int*)d_in[2];
    const float* rg   = (const float*)d_in[3];
    const float* hg   = (const float*)d_in[4];
    const float* wR   = (const float*)d_in[5];
    const float* bR   = (const float*)d_in[6];
    const float* wH   = (const float*)d_in[7];
    const float* bH   = (const float*)d_in[8];
    float* out = (float*)d_out;

    if (ws_size >= WS_NEED) {
        char* ws = (char*)d_ws;
        hipMemsetAsync(ws + ZOFF, 0, 64, stream);
        hipLaunchKernelGGL(pack_weights, dim3(288), dim3(256), 0, stream,
                           wR, wH, rg, hg, (short*)(ws + WPACK_OFF));
        hipLaunchKernelGGL(pack_jb, dim3(225), dim3(256), 0, stream,
                           corr, (int*)(ws + JB_OFF));
        hipLaunchKernelGGL(nchw2nhwc, dim3(5, 75, 4), dim3(256), 0, stream,
                           xrgb, yhsi, (short*)ws);
        hipLaunchKernelGGL(conv_mfma, dim3(285, 4, 2), dim3(256), 0, stream,
                           (const char*)ws, (const short*)(ws + WPACK_OFF), bR, bH, out);
    } else {
        int total = 4 * HW;
        hipLaunchKernelGGL(fused_gather_conv, dim3((total + 255) / 256), dim3(256), 0, stream,
                           xrgb, yhsi, corr, rg, hg, wR, bR, wH, bH, out);
    }
}